// Round 7
// baseline (293.630 us; speedup 1.0000x reference)
//
#include <hip/hip_runtime.h>

// B=16, C=64, H=W=192, K=3 (fixed).
// Kernel 1: ker[b,c,i,j] from the tiny MLP (16 blocks, writes 9216 floats to ws).
// Kernel 2 (v10): EXACT v9 structure (best total 271.2 us) with ONE change:
// all x0 loads are __builtin_nontemporal_load (nt hint, evict-first L2/L3).
//   Theory: six structurally different conv variants all plateau at
//   88-95 us / ~2.4 TB/s with every pipe idle -> bound is external to
//   structure. Prime suspect: DRAM read/write turnaround on the finely
//   interleaved mixed stream (pure-write fill gets 6.5 TB/s on the same
//   HW). NT loads keep reads out of L3 so the 151 MB output stream can
//   live in the 256 MiB L3 and drain in large bursts instead of
//   CU-interleaved lines. Signature if active: conv FETCH_SIZE ~84->150 MB.

#define BB 16
#define CC 64
#define HH 192
#define WW 192
#define KERLEN (CC * 9)     // 576 per batch
#define QW (WW / 4)         // 48 quads per row
#define RPT 4               // output rows per thread
#define TPP (QW * (HH / RPT))   // 48*48 = 2304 tasks per plane
#define BPP (TPP / 256)         // 9 blocks per plane

typedef float f4 __attribute__((ext_vector_type(4)));

// ---- Kernel 1: generate the 1024 per-(b,c) 3x3 kernels into d_ws ----
__global__ __launch_bounds__(256) void gen_kernels(
    const float* __restrict__ d,   // (B, C)
    const float* __restrict__ w1,  // (C, C)
    const float* __restrict__ w2,  // (C*9, C)
    float* __restrict__ ker)       // (B*C*9)
{
    __shared__ float dd[CC];
    __shared__ float hid[CC];
    const int b = blockIdx.x;
    const int t = threadIdx.x;

    if (t < CC) dd[t] = d[b * CC + t];
    __syncthreads();

    if (t < CC) {
        const float* w1r = w1 + t * CC;
        float acc = 0.f;
        #pragma unroll 8
        for (int m = 0; m < CC; ++m) acc += dd[m] * w1r[m];
        hid[t] = acc > 0.f ? acc : 0.1f * acc;
    }
    __syncthreads();

    for (int o = t; o < KERLEN; o += 256) {
        const float* w2r = w2 + o * CC;
        float acc = 0.f;
        #pragma unroll 8
        for (int k = 0; k < CC; ++k) acc += hid[k] * w2r[k];
        ker[b * KERLEN + o] = acc;
    }
}

// ---- Kernel 2: depthwise 3x3, hoisted NT loads, plain stores ----
__global__ __launch_bounds__(256, 8) void dconv3x3_v10(
    const float* __restrict__ x,    // (B*C, H, W)
    const float* __restrict__ ker,  // (B*C, 9)
    float* __restrict__ out)        // (B*C, H, W)
{
    const int blk = blockIdx.x;
    const int bc  = blk / BPP;
    const int sub = blk - bc * BPP;

    // block-uniform coefficients -> scalar loads (SGPRs)
    const float* kp = ker + bc * 9;
    const float k00 = kp[0], k01 = kp[1], k02 = kp[2];
    const float k10 = kp[3], k11 = kp[4], k12 = kp[5];
    const float k20 = kp[6], k21 = kp[7], k22 = kp[8];

    const int task = sub * 256 + threadIdx.x;   // 0..2303
    const int rg   = task / QW;                 // row-group 0..47
    const int qw   = task - rg * QW;            // quad col 0..47
    const int w    = qw * 4;
    const int r0   = rg * RPT;

    const bool hasL = (qw > 0);
    const bool hasR = (qw < QW - 1);
    const int  offL = hasL ? -1 : 0;            // safe clamped offsets
    const int  offR = hasR ?  4 : 0;

    const float* __restrict__ xp = x   + (size_t)bc * HH * WW + w;
    float* __restrict__       op = out + (size_t)bc * HH * WW + w;

    f4    c[RPT + 2];
    float l[RPT + 2], r[RPT + 2];
    const f4 zero = {0.f, 0.f, 0.f, 0.f};

    // All 6 row-loads issued before any use, ALL via nontemporal_load
    // (the single change vs v9): reads don't allocate in L3.
    #pragma unroll
    for (int j = 0; j < RPT + 2; ++j) {
        const int rr  = r0 - 1 + j;
        const int rcl = rr < 0 ? 0 : (rr >= HH ? HH - 1 : rr);
        const float* p = xp + rcl * WW;
        const f4 v     = __builtin_nontemporal_load((const f4*)p);
        const float lv = __builtin_nontemporal_load(p + offL);
        const float rv = __builtin_nontemporal_load(p + offR);
        const bool ok  = (rr >= 0) & (rr < HH);
        c[j] = ok ? v : zero;
        l[j] = (ok && hasL) ? lv : 0.f;
        r[j] = (ok && hasR) ? rv : 0.f;
    }

    #pragma unroll
    for (int i = 0; i < RPT; ++i) {
        const f4 ca = c[i], cb = c[i + 1], cd = c[i + 2];
        const float la = l[i], lb = l[i + 1], lc = l[i + 2];
        const float ra = r[i], rb = r[i + 1], rc = r[i + 2];

        f4 o;
        o.x = k00 * la   + k01 * ca.x + k02 * ca.y
            + k10 * lb   + k11 * cb.x + k12 * cb.y
            + k20 * lc   + k21 * cd.x + k22 * cd.y;
        o.y = k00 * ca.x + k01 * ca.y + k02 * ca.z
            + k10 * cb.x + k11 * cb.y + k12 * cb.z
            + k20 * cd.x + k21 * cd.y + k22 * cd.z;
        o.z = k00 * ca.y + k01 * ca.z + k02 * ca.w
            + k10 * cb.y + k11 * cb.z + k12 * cb.w
            + k20 * cd.y + k21 * cd.z + k22 * cd.w;
        o.w = k00 * ca.z + k01 * ca.w + k02 * ra
            + k10 * cb.z + k11 * cb.w + k12 * rb
            + k20 * cd.z + k21 * cd.w + k22 * rc;

        // plain store: write-allocates in L2/L3, drains in large bursts
        *(f4*)(op + (size_t)(r0 + i) * WW) = o;
    }
}

extern "C" void kernel_launch(void* const* d_in, const int* in_sizes, int n_in,
                              void* d_out, int out_size, void* d_ws, size_t ws_size,
                              hipStream_t stream) {
    const float* x0 = (const float*)d_in[0];  // (16,64,192,192)
    const float* d  = (const float*)d_in[1];  // (16,64)
    const float* w1 = (const float*)d_in[2];  // (64,64)
    const float* w2 = (const float*)d_in[3];  // (576,64)
    float* out = (float*)d_out;
    float* ker = (float*)d_ws;                // 9216 floats

    gen_kernels<<<BB, 256, 0, stream>>>(d, w1, w2, ker);
    dconv3x3_v10<<<BB * CC * BPP, 256, 0, stream>>>(x0, ker, out);
}

// Round 8
// 290.539 us; speedup vs baseline: 1.0106x; 1.0106x over previous
//
#include <hip/hip_runtime.h>

// B=16, C=64, H=W=192, K=3 (fixed).
// Kernel 1: tiny MLP -> per-(b,c) 3x3 kernels, stored PADDED to 16 floats
//   per plane (aligned f4 loads in kernel 2). 64 KB of workspace.
// Kernel 2 (v11): COPY-STRUCTURED depthwise 3x3.
//   Evidence: conv duration is invariant (~91us) to bytes moved (157-308MB),
//   occupancy, VGPRs, staging style, store/load cache policy. The only
//   memory pattern proven to stream at 6.3 TB/s on this chip (m13 float4
//   copy) is a grid-stride linear sweep: one compact window sweeping the
//   whole array. All prior variants used scattered block-owned 2D tiles.
//   v11: grid-stride over (plane, row-pair, quad) linear index; 524288
//   lanes x 9 iterations, consecutive lanes = consecutive quads. Per pair:
//   4 aligned f4 row loads + 8 edge dwords (re-reads L2-hot), 3 ker loads
//   (wave-uniform broadcast), 2 plain f4 stores. No reg cap; unroll 3.

#define BB 16
#define CC 64
#define HH 192
#define WW 192
#define KERLEN (CC * 9)         // 576 per batch (compute side)
#define QW (WW / 4)             // 48 quads per row
#define NPLANE (BB * CC)        // 1024
#define PPP (96 * QW)           // 4608 row-pairs*quads per plane
#define TOTALP (NPLANE * PPP)   // 4,718,592 pairs
#define NBLK 2048
#define NTHR (NBLK * 256)       // 524,288 threads
#define NIT (TOTALP / NTHR)     // 9 (exact)
#define PLSZ (HH * WW)          // 36864 floats per plane

typedef float f4 __attribute__((ext_vector_type(4)));

// ---- Kernel 1: generate the 1024 per-(b,c) 3x3 kernels into d_ws ----
// Layout: plane p's 9 coeffs at ker[p*16 + 0..8] (16-float stride, 64B align)
__global__ __launch_bounds__(256) void gen_kernels(
    const float* __restrict__ d,   // (B, C)
    const float* __restrict__ w1,  // (C, C)
    const float* __restrict__ w2,  // (C*9, C)
    float* __restrict__ ker)       // (B*C*16)
{
    __shared__ float dd[CC];
    __shared__ float hid[CC];
    const int b = blockIdx.x;
    const int t = threadIdx.x;

    if (t < CC) dd[t] = d[b * CC + t];
    __syncthreads();

    if (t < CC) {
        const float* w1r = w1 + t * CC;
        float acc = 0.f;
        #pragma unroll 8
        for (int m = 0; m < CC; ++m) acc += dd[m] * w1r[m];
        hid[t] = acc > 0.f ? acc : 0.1f * acc;
    }
    __syncthreads();

    for (int o = t; o < KERLEN; o += 256) {
        const float* w2r = w2 + o * CC;
        float acc = 0.f;
        #pragma unroll 8
        for (int k = 0; k < CC; ++k) acc += hid[k] * w2r[k];
        const int c = o / 9;
        const int j = o - c * 9;
        ker[(b * CC + c) * 16 + j] = acc;
    }
}

// ---- Kernel 2: depthwise 3x3, grid-stride linear sweep ----
__global__ __launch_bounds__(256) void dconv3x3_v11(
    const float* __restrict__ x,    // (B*C, H, W)
    const float* __restrict__ ker,  // (B*C, 16)
    float* __restrict__ out)        // (B*C, H, W)
{
    const int tid = blockIdx.x * 256 + threadIdx.x;   // 0..524287
    const f4 zero = {0.f, 0.f, 0.f, 0.f};

    #pragma unroll 3
    for (int it = 0; it < NIT; ++it) {
        const int idx = tid + it * NTHR;              // pair index
        const int p   = idx / PPP;                    // plane 0..1023
        const int rem = idx - p * PPP;
        const int rp  = rem / QW;                     // row-pair 0..95
        const int q   = rem - rp * QW;                // quad 0..47

        const int r0 = rp * 2;                        // out rows r0, r0+1
        const bool okm = (rp > 0);                    // row r0-1 valid
        const bool okp = (rp < 95);                   // row r0+2 valid
        const bool hasL = (q > 0);
        const bool hasR = (q < QW - 1);
        const int offL = hasL ? -1 : 0;
        const int offR = hasR ?  4 : 0;

        // kernel coeffs: wave-mostly-uniform addresses -> broadcast loads
        const float* kp = ker + p * 16;
        const f4 ka = *(const f4*)kp;         // k00 k01 k02 k10
        const f4 kb = *(const f4*)(kp + 4);   // k11 k12 k20 k21
        const float k22 = kp[8];
        const float k00 = ka.x, k01 = ka.y, k02 = ka.z, k10 = ka.w;
        const float k11 = kb.x, k12 = kb.y, k20 = kb.z, k21 = kb.w;

        const float* base = x + (size_t)p * PLSZ + r0 * WW + q * 4;

        // 4 input rows: a = r0-1 (clamped), b = r0, c = r0+1, d = r0+2 (clamped)
        const float* pa = base + (okm ? -WW : 0);
        const float* pb = base;
        const float* pc = base + WW;
        const float* pd = base + (okp ? 2 * WW : WW);

        f4 va = *(const f4*)pa;  float lA = pa[offL], rA = pa[offR];
        f4 vb = *(const f4*)pb;  float lB = pb[offL], rB = pb[offR];
        f4 vc = *(const f4*)pc;  float lC = pc[offL], rC = pc[offR];
        f4 vd = *(const f4*)pd;  float lD = pd[offL], rD = pd[offR];

        // zero-padding semantics
        va = okm ? va : zero;
        lA = (okm && hasL) ? lA : 0.f;  rA = (okm && hasR) ? rA : 0.f;
        vd = okp ? vd : zero;
        lD = (okp && hasL) ? lD : 0.f;  rD = (okp && hasR) ? rD : 0.f;
        lB = hasL ? lB : 0.f;  rB = hasR ? rB : 0.f;
        lC = hasL ? lC : 0.f;  rC = hasR ? rC : 0.f;

        // out row r0: rows a,b,c
        f4 o0;
        o0.x = k00 * lA   + k01 * va.x + k02 * va.y
             + k10 * lB   + k11 * vb.x + k12 * vb.y
             + k20 * lC   + k21 * vc.x + k22 * vc.y;
        o0.y = k00 * va.x + k01 * va.y + k02 * va.z
             + k10 * vb.x + k11 * vb.y + k12 * vb.z
             + k20 * vc.x + k21 * vc.y + k22 * vc.z;
        o0.z = k00 * va.y + k01 * va.z + k02 * va.w
             + k10 * vb.y + k11 * vb.z + k12 * vb.w
             + k20 * vc.y + k21 * vc.z + k22 * vc.w;
        o0.w = k00 * va.z + k01 * va.w + k02 * rA
             + k10 * vb.z + k11 * vb.w + k12 * rB
             + k20 * vc.z + k21 * vc.w + k22 * rC;

        // out row r0+1: rows b,c,d
        f4 o1;
        o1.x = k00 * lB   + k01 * vb.x + k02 * vb.y
             + k10 * lC   + k11 * vc.x + k12 * vc.y
             + k20 * lD   + k21 * vd.x + k22 * vd.y;
        o1.y = k00 * vb.x + k01 * vb.y + k02 * vb.z
             + k10 * vc.x + k11 * vc.y + k12 * vc.z
             + k20 * vd.x + k21 * vd.y + k22 * vd.z;
        o1.z = k00 * vb.y + k01 * vb.z + k02 * vb.w
             + k10 * vc.y + k11 * vc.z + k12 * vc.w
             + k20 * vd.y + k21 * vd.z + k22 * vd.w;
        o1.w = k00 * vb.z + k01 * vb.w + k02 * rB
             + k10 * vc.z + k11 * vc.w + k12 * rC
             + k20 * vd.z + k21 * vd.w + k22 * rD;

        float* op = out + (size_t)p * PLSZ + r0 * WW + q * 4;
        *(f4*)op        = o0;
        *(f4*)(op + WW) = o1;
    }
}

extern "C" void kernel_launch(void* const* d_in, const int* in_sizes, int n_in,
                              void* d_out, int out_size, void* d_ws, size_t ws_size,
                              hipStream_t stream) {
    const float* x0 = (const float*)d_in[0];  // (16,64,192,192)
    const float* d  = (const float*)d_in[1];  // (16,64)
    const float* w1 = (const float*)d_in[2];  // (64,64)
    const float* w2 = (const float*)d_in[3];  // (576,64)
    float* out = (float*)d_out;
    float* ker = (float*)d_ws;                // 1024*16 floats = 64 KB

    gen_kernels<<<BB, 256, 0, stream>>>(d, w1, w2, ker);
    dconv3x3_v11<<<NBLK, 256, 0, stream>>>(x0, ker, out);
}

// Round 9
// 275.543 us; speedup vs baseline: 1.0656x; 1.0544x over previous
//
#include <hip/hip_runtime.h>

// B=16, C=64, H=W=192, K=3 (fixed).
// Kernel 1: tiny MLP -> per-(b,c) 3x3 kernels, PADDED to 16 floats/plane.
// Kernel 2 (v12): depthwise 3x3, WIDE-LANE + SHUFFLE-HALO.
//   Evidence: conv duration invariant to bytes (231 vs 301 MB @ ~91us) ->
//   VMEM-request-bound, not BW-bound. Prior variants spent 12/22 VMEM
//   instrs on single-dword edge gathers (64 lanes -> 12-16 cache lines,
//   ~f4 cost for 1/4 the data), and __launch_bounds__(256,8) had silently
//   pinned VGPR=32, serializing the "hoisted" loads.
//   v12: each lane owns 12 contiguous floats (3 aligned f4) of a row; 16
//   lanes = one full row. Halo floats come from neighbor lanes via 2
//   __shfl per row (not memory). 18 f4 loads hoisted, no reg cap, all
//   VMEM is clean 16B-coalesced. Per-elem VMEM instrs: 1.4 -> 0.63.

#define BB 16
#define CC 64
#define HH 192
#define WW 192
#define KERLEN (CC * 9)
#define PLSZ (HH * WW)      // 36864 floats per plane
#define RPT 4               // output rows per thread
#define NLANE 16            // lanes per row
#define COLS 12             // floats per lane (16*12 = 192)
#define TPP (NLANE * (HH / RPT))   // 768 threads per plane
#define BPP (TPP / 256)            // 3 blocks per plane

typedef float f4 __attribute__((ext_vector_type(4)));

// ---- Kernel 1: generate per-(b,c) 3x3 kernels into d_ws (16-float stride) ----
__global__ __launch_bounds__(256) void gen_kernels(
    const float* __restrict__ d,   // (B, C)
    const float* __restrict__ w1,  // (C, C)
    const float* __restrict__ w2,  // (C*9, C)
    float* __restrict__ ker)       // (B*C*16)
{
    __shared__ float dd[CC];
    __shared__ float hid[CC];
    const int b = blockIdx.x;
    const int t = threadIdx.x;

    if (t < CC) dd[t] = d[b * CC + t];
    __syncthreads();

    if (t < CC) {
        const float* w1r = w1 + t * CC;
        float acc = 0.f;
        #pragma unroll 8
        for (int m = 0; m < CC; ++m) acc += dd[m] * w1r[m];
        hid[t] = acc > 0.f ? acc : 0.1f * acc;
    }
    __syncthreads();

    for (int o = t; o < KERLEN; o += 256) {
        const float* w2r = w2 + o * CC;
        float acc = 0.f;
        #pragma unroll 8
        for (int k = 0; k < CC; ++k) acc += hid[k] * w2r[k];
        const int c = o / 9;
        const int j = o - c * 9;
        ker[(b * CC + c) * 16 + j] = acc;
    }
}

// ---- Kernel 2: depthwise 3x3, wide lanes + shuffle halo ----
__global__ __launch_bounds__(256) void dconv3x3_v12(
    const float* __restrict__ x,    // (B*C, H, W)
    const float* __restrict__ ker,  // (B*C, 16)
    float* __restrict__ out)        // (B*C, H, W)
{
    const int blk  = blockIdx.x;
    const int p    = blk / BPP;                 // plane 0..1023 (block-uniform)
    const int chnk = blk - p * BPP;
    const int task = chnk * 256 + threadIdx.x;  // 0..767
    const int rg   = task >> 4;                 // row-group 0..47
    const int m    = task & 15;                 // col-chunk 0..15
    const int r0   = rg * RPT;
    const int col  = m * COLS;

    // block-uniform coefficients -> SGPRs
    const float* kp = ker + p * 16;
    const float k00 = kp[0], k01 = kp[1], k02 = kp[2];
    const float k10 = kp[3], k11 = kp[4], k12 = kp[5];
    const float k20 = kp[6], k21 = kp[7], k22 = kp[8];

    const float* __restrict__ xp = x   + (size_t)p * PLSZ + col;
    float* __restrict__       op = out + (size_t)p * PLSZ + col;

    const bool hasL = (m > 0);
    const bool hasR = (m < NLANE - 1);
    const f4 zero = {0.f, 0.f, 0.f, 0.f};

    // ---- phase 1: issue ALL 18 row loads (6 rows x 3 f4), fully independent ----
    f4 c[RPT + 2][3];
    #pragma unroll
    for (int j = 0; j < RPT + 2; ++j) {
        const int rr  = r0 - 1 + j;
        const int rcl = rr < 0 ? 0 : (rr >= HH ? HH - 1 : rr);
        const f4* pr  = (const f4*)(xp + rcl * WW);
        c[j][0] = pr[0];
        c[j][1] = pr[1];
        c[j][2] = pr[2];
    }

    // ---- phase 2: row-validity masking + halo via cross-lane shuffle ----
    // All 16 lanes of a row-group share the same row validity, so masking
    // before the shuffle is consistent within the group; shuffles that cross
    // a 16-lane group boundary are masked by hasL/hasR (image edge).
    float le[RPT + 2], re[RPT + 2];
    #pragma unroll
    for (int j = 0; j < RPT + 2; ++j) {
        const int rr = r0 - 1 + j;
        const bool ok = (unsigned)rr < (unsigned)HH;
        c[j][0] = ok ? c[j][0] : zero;
        c[j][1] = ok ? c[j][1] : zero;
        c[j][2] = ok ? c[j][2] : zero;
        const float lv = __shfl_up(c[j][2].w, 1);    // lane m-1's col 12m-1
        const float rv = __shfl_down(c[j][0].x, 1);  // lane m+1's col 12m+12
        le[j] = hasL ? lv : 0.f;
        re[j] = hasR ? rv : 0.f;
    }

    // one input row's contribution to one output f4 (s = which of 3 f4s)
    auto part = [&](int j, int s, float kl, float kc, float kr) -> f4 {
        const f4 cc     = c[j][s];
        const float lft = (s == 0) ? le[j] : c[j][s - 1].w;
        const float rgt = (s == 2) ? re[j] : c[j][s + 1].x;
        f4 t;
        t.x = kl * lft  + kc * cc.x + kr * cc.y;
        t.y = kl * cc.x + kc * cc.y + kr * cc.z;
        t.z = kl * cc.y + kc * cc.z + kr * cc.w;
        t.w = kl * cc.z + kc * cc.w + kr * rgt;
        return t;
    };

    // ---- phase 3: compute + store (3 f4 per output row, 16B coalesced) ----
    #pragma unroll
    for (int i = 0; i < RPT; ++i) {
        f4* orow = (f4*)(op + (size_t)(r0 + i) * WW);
        #pragma unroll
        for (int s = 0; s < 3; ++s) {
            const f4 t0 = part(i,     s, k00, k01, k02);
            const f4 t1 = part(i + 1, s, k10, k11, k12);
            const f4 t2 = part(i + 2, s, k20, k21, k22);
            f4 o;
            o.x = t0.x + t1.x + t2.x;
            o.y = t0.y + t1.y + t2.y;
            o.z = t0.z + t1.z + t2.z;
            o.w = t0.w + t1.w + t2.w;
            orow[s] = o;
        }
    }
}

extern "C" void kernel_launch(void* const* d_in, const int* in_sizes, int n_in,
                              void* d_out, int out_size, void* d_ws, size_t ws_size,
                              hipStream_t stream) {
    const float* x0 = (const float*)d_in[0];  // (16,64,192,192)
    const float* d  = (const float*)d_in[1];  // (16,64)
    const float* w1 = (const float*)d_in[2];  // (64,64)
    const float* w2 = (const float*)d_in[3];  // (576,64)
    float* out = (float*)d_out;
    float* ker = (float*)d_ws;                // 1024*16 floats = 64 KB

    gen_kernels<<<BB, 256, 0, stream>>>(d, w1, w2, ker);
    dconv3x3_v12<<<BB * CC * BPP, 256, 0, stream>>>(x0, ker, out);
}